// Round 1
// baseline (888.627 us; speedup 1.0000x reference)
//
#include <hip/hip_runtime.h>

#define HH 512
#define WW 512
#define NPIX (HH*WW)      // 2^18
#define BATCH 16
#define NIMG 32           // 16 ref + 16 tgt

// ---------------- Stage 1: luminance ----------------
__global__ void k_lum(const float* __restrict__ ref, const float* __restrict__ tgt,
                      float* __restrict__ lum) {
    int idx = blockIdx.x * 256 + threadIdx.x;
    int img = idx >> 18;
    int pix = idx & (NPIX - 1);
    const float* src = (img < BATCH) ? (ref + (size_t)img * 3 * NPIX)
                                     : (tgt + (size_t)(img - BATCH) * 3 * NPIX);
    float r = src[pix];
    float g = src[NPIX + pix];
    float b = src[2 * NPIX + pix];
    lum[idx] = 0.299f * r + 0.587f * g + 0.114f * b;
}

// ---------------- Stage 2: sobel magnitude -> edge byte ----------------
__global__ void k_sobel(const float* __restrict__ lum, unsigned char* __restrict__ E) {
    int idx = blockIdx.x * 256 + threadIdx.x;
    int img = idx >> 18;
    int pix = idx & (NPIX - 1);
    int y = pix >> 9, x = pix & 511;
    const float* L = lum + (size_t)img * NPIX;

    float v[3][3];
#pragma unroll
    for (int dy = 0; dy < 3; ++dy) {
#pragma unroll
        for (int dx = 0; dx < 3; ++dx) {
            int yy = y + dy - 1, xx = x + dx - 1;
            v[dy][dx] = ((unsigned)yy < HH && (unsigned)xx < WW) ? L[yy * WW + xx] : 0.0f;
        }
    }
    float gx = (v[0][2] - v[0][0]) + 2.0f * (v[1][2] - v[1][0]) + (v[2][2] - v[2][0]);
    float gy = (v[2][0] - v[0][0]) + 2.0f * (v[2][1] - v[0][1]) + (v[2][2] - v[0][2]);
    float grad = sqrtf(gx * gx + gy * gy + 1e-12f);
    E[idx] = (grad > 0.1f) ? 1 : 0;
}

// ---------------- Stage 3: 5x5 binary dilation ----------------
__global__ void k_dilate(const unsigned char* __restrict__ E, unsigned char* __restrict__ Ed) {
    int idx = blockIdx.x * 256 + threadIdx.x;
    int img = idx >> 18;
    int pix = idx & (NPIX - 1);
    int y = pix >> 9, x = pix & 511;
    const unsigned char* Ei = E + (size_t)img * NPIX;
    int m = 0;
#pragma unroll
    for (int dy = -2; dy <= 2; ++dy) {
        int yy = y + dy;
        if ((unsigned)yy >= HH) continue;
#pragma unroll
        for (int dx = -2; dx <= 2; ++dx) {
            int xx = x + dx;
            if ((unsigned)xx >= WW) continue;
            m |= Ei[yy * WW + xx];
        }
    }
    Ed[idx] = (unsigned char)m;
}

// ---------------- Stage 4: masked 7x7 local variance, per-image reduction ----
__inline__ __device__ float wave_reduce(float v) {
#pragma unroll
    for (int o = 32; o > 0; o >>= 1) v += __shfl_down(v, o);
    return v;
}

__global__ void k_var(const float* __restrict__ lum, const unsigned char* __restrict__ E,
                      const unsigned char* __restrict__ Ed, double* __restrict__ acc) {
    int img = blockIdx.x >> 10;                      // 1024 blocks / image
    int pix = ((blockIdx.x & 1023) << 8) + threadIdx.x;
    int y = pix >> 9, x = pix & 511;
    const float* L = lum + (size_t)img * NPIX;
    const unsigned char* Ei = E + (size_t)img * NPIX;
    const unsigned char* Edi = Ed + (size_t)img * NPIX;

    float s1p = 0.f, s2p = 0.f, cp = 0.f;
    float s1b = 0.f, s2b = 0.f, cb = 0.f;
    for (int dy = -3; dy <= 3; ++dy) {
        int yy = y + dy;
        if ((unsigned)yy >= HH) continue;
        int rb = yy * WW;
        for (int dx = -3; dx <= 3; ++dx) {
            int xx = x + dx;
            if ((unsigned)xx >= WW) continue;
            int q = rb + xx;
            float l = L[q];
            int e = Ei[q], ed = Edi[q];
            float mp = (float)(ed & (e ^ 1));
            float mb = (float)(ed ^ 1);
            cp += mp; s1p += mp * l; s2p += mp * l * l;
            cb += mb; s1b += mb * l; s2b += mb * l * l;
        }
    }
    int e0 = Ei[pix], ed0 = Edi[pix];
    float mp0 = (float)(ed0 & (e0 ^ 1));
    float mb0 = (float)(ed0 ^ 1);

    float Cp = fmaxf(cp, 1.0f);
    float meanp = s1p / Cp;
    float varp = fmaxf(s2p / Cp - meanp * meanp, 0.0f);
    float Cb = fmaxf(cb, 1.0f);
    float meanb = s1b / Cb;
    float varb = fmaxf(s2b / Cb - meanb * meanb, 0.0f);

    float c0 = varp * mp0;   // var_prox numerator contribution
    float c1 = mp0;          // prox mask count
    float c2 = varb * mb0;   // var_bg numerator contribution
    float c3 = mb0;          // bg mask count

    // block reduce 4 values (4 waves of 64)
    __shared__ float sh[4][4];
    int lane = threadIdx.x & 63;
    int wid = threadIdx.x >> 6;
    c0 = wave_reduce(c0); c1 = wave_reduce(c1); c2 = wave_reduce(c2); c3 = wave_reduce(c3);
    if (lane == 0) { sh[wid][0] = c0; sh[wid][1] = c1; sh[wid][2] = c2; sh[wid][3] = c3; }
    __syncthreads();
    if (threadIdx.x == 0) {
        double t0 = 0, t1 = 0, t2 = 0, t3 = 0;
        for (int w = 0; w < 4; ++w) { t0 += sh[w][0]; t1 += sh[w][1]; t2 += sh[w][2]; t3 += sh[w][3]; }
        atomicAdd(&acc[img * 4 + 0], t0);
        atomicAdd(&acc[img * 4 + 1], t1);
        atomicAdd(&acc[img * 4 + 2], t2);
        atomicAdd(&acc[img * 4 + 3], t3);
    }
}

// ---------------- Stage 5: per-image flags + output ----------------
__global__ void k_out(const unsigned char* __restrict__ E, const unsigned char* __restrict__ Ed,
                      const double* __restrict__ acc, float* __restrict__ out) {
    int idx = blockIdx.x * 256 + threadIdx.x;
    int b = idx >> 18;
    int pix = idx & (NPIX - 1);

    const double* ar = acc + (size_t)b * 4;
    const double* at = acc + (size_t)(b + BATCH) * 4;
    double vpr = ar[0] / fmax(ar[1], 1.0);
    double vbr = ar[2] / fmax(ar[3], 1.0);
    bool irr = (vpr / (vbr + 1e-12)) > 2.0;
    double vpt = at[0] / fmax(at[1], 1.0);
    double vbt = at[2] / fmax(at[3], 1.0);
    bool irt = (vpt / (vbt + 1e-12)) > 2.0;

    size_t pr = (size_t)b * NPIX + pix;
    size_t pt = (size_t)(b + BATCH) * NPIX + pix;
    int mpr = Ed[pr] & (E[pr] ^ 1);
    int mpt = Ed[pt] & (E[pt] ^ 1);

    float a = (mpt && irt) ? 1.0f : 0.0f;
    float r = (mpr && irr) ? 1.0f : 0.0f;
    out[idx] = fmaxf(a - r, 0.0f);
}

extern "C" void kernel_launch(void* const* d_in, const int* in_sizes, int n_in,
                              void* d_out, int out_size, void* d_ws, size_t ws_size,
                              hipStream_t stream) {
    const float* ref = (const float*)d_in[0];
    const float* tgt = (const float*)d_in[1];
    float* out = (float*)d_out;

    char* ws = (char*)d_ws;
    double* acc = (double*)ws;                                   // 32*4 doubles = 1 KB
    float* lum = (float*)(ws + 1024);                            // 32 * 256K * 4B = 32 MB
    unsigned char* E = (unsigned char*)(ws + 1024 + (size_t)NIMG * NPIX * 4);  // 8 MB
    unsigned char* Ed = E + (size_t)NIMG * NPIX;                 // 8 MB

    hipMemsetAsync(acc, 0, NIMG * 4 * sizeof(double), stream);

    int nAll = NIMG * NPIX;          // 8388608
    int nOut = BATCH * NPIX;         // 4194304
    k_lum<<<nAll / 256, 256, 0, stream>>>(ref, tgt, lum);
    k_sobel<<<nAll / 256, 256, 0, stream>>>(lum, E);
    k_dilate<<<nAll / 256, 256, 0, stream>>>(E, Ed);
    k_var<<<nAll / 256, 256, 0, stream>>>(lum, E, Ed, acc);
    k_out<<<nOut / 256, 256, 0, stream>>>(E, Ed, acc, out);
}

// Round 2
// 320.396 us; speedup vs baseline: 2.7735x; 2.7735x over previous
//
#include <hip/hip_runtime.h>

#define HH 512
#define WW 512
#define NPIX (HH*WW)      // 2^18
#define BATCH 16
#define NIMG 32           // 16 ref + 16 tgt

typedef unsigned char uchar;

// ---------------- Stage 1: luminance (float4 vectorized) ----------------
__global__ __launch_bounds__(256) void k_lum(const float4* __restrict__ ref,
                                             const float4* __restrict__ tgt,
                                             float4* __restrict__ lum) {
    int idx = blockIdx.x * 256 + threadIdx.x;     // NIMG * NPIX/4 threads
    int img = idx >> 16;                          // NPIX/4 = 65536
    int p4 = idx & 65535;
    const float4* src = (img < BATCH) ? (ref + (size_t)img * 3 * 65536)
                                      : (tgt + (size_t)(img - BATCH) * 3 * 65536);
    float4 r = src[p4];
    float4 g = src[65536 + p4];
    float4 b = src[131072 + p4];
    float4 o;
    o.x = 0.299f * r.x + 0.587f * g.x + 0.114f * b.x;
    o.y = 0.299f * r.y + 0.587f * g.y + 0.114f * b.y;
    o.z = 0.299f * r.z + 0.587f * g.z + 0.114f * b.z;
    o.w = 0.299f * r.w + 0.587f * g.w + 0.114f * b.w;
    lum[idx] = o;
}

// ---------------- Stage 2+3 fused: sobel edge + 5x5 dilation (LDS tiled) ----
#define SS 38   // lum tile: 32 + 2*3 halo
#define ES 36   // E tile:   32 + 2*2 halo

__global__ __launch_bounds__(256) void k_sobel_dilate(const float* __restrict__ lum,
                                                      uchar* __restrict__ E,
                                                      uchar* __restrict__ Ed) {
    __shared__ float Ls[SS * SS];
    __shared__ int Es[ES * ES];   // int to keep LDS accesses word-granular

    int bi = blockIdx.x;
    int img = bi >> 8;            // 256 tiles per image
    int t = bi & 255;
    int y0 = (t >> 4) << 5;
    int x0 = (t & 15) << 5;
    const float* L = lum + (size_t)img * NPIX;

    for (int i = threadIdx.x; i < SS * SS; i += 256) {
        int r = i / SS, c = i - r * SS;
        int gy = y0 - 3 + r, gx = x0 - 3 + c;
        Ls[i] = ((unsigned)gy < HH && (unsigned)gx < WW) ? L[gy * WW + gx] : 0.0f;
    }
    __syncthreads();

    for (int i = threadIdx.x; i < ES * ES; i += 256) {
        int r = i / ES, c = i - r * ES;
        int gy = y0 - 2 + r, gx = x0 - 2 + c;
        int e = 0;
        if ((unsigned)gy < HH && (unsigned)gx < WW) {
            int base = (r + 1) * SS + (c + 1);   // lum tile offset of this pixel
            float v00 = Ls[base - SS - 1], v01 = Ls[base - SS], v02 = Ls[base - SS + 1];
            float v10 = Ls[base - 1],                            v12 = Ls[base + 1];
            float v20 = Ls[base + SS - 1], v21 = Ls[base + SS], v22 = Ls[base + SS + 1];
            float gxv = (v02 - v00) + 2.0f * (v12 - v10) + (v22 - v20);
            float gyv = (v20 - v00) + 2.0f * (v21 - v01) + (v22 - v02);
            float grad = sqrtf(gxv * gxv + gyv * gyv + 1e-12f);
            e = (grad > 0.1f) ? 1 : 0;
        }
        Es[i] = e;
    }
    __syncthreads();

#pragma unroll
    for (int k = 0; k < 4; ++k) {
        int j = threadIdx.x + (k << 8);   // 0..1023 over 32x32 tile
        int y = j >> 5, x = j & 31;
        int m = 0;
#pragma unroll
        for (int dy = 0; dy < 5; ++dy)
#pragma unroll
            for (int dx = 0; dx < 5; ++dx)
                m |= Es[(y + dy) * ES + (x + dx)];
        size_t q = (size_t)img * NPIX + (y0 + y) * WW + (x0 + x);
        E[q] = (uchar)Es[(y + 2) * ES + (x + 2)];
        Ed[q] = (uchar)m;
    }
}

// ---------------- Stage 4: masked 7x7 local variance (LDS separable) -------
// M_prox = Edil & !E = (1-E) - (1-Edil)  (dilation includes center => E<=Edil)
// So box sums over u=(1-E) and v=(1-Edil) give both masks:
//   prox sums = u-sums - v-sums ; bg sums = v-sums.
#define VS 38              // 32 + 2*3 halo
#define HSTRIDE 7          // pad 6 floats -> 7: gcd(7,32)=1, conflict-free

__inline__ __device__ float wave_reduce(float v) {
#pragma unroll
    for (int o = 32; o > 0; o >>= 1) v += __shfl_down(v, o);
    return v;
}

__global__ __launch_bounds__(256) void k_var(const float* __restrict__ lum,
                                             const uchar* __restrict__ E,
                                             const uchar* __restrict__ Ed,
                                             double* __restrict__ acc) {
    __shared__ uint2 S[VS * VS];                 // (lum bits, mask u|v<<1): 11552 B
    __shared__ float Hs[VS * 32 * HSTRIDE];      // horizontal 7-sums: 34048 B
    __shared__ float red[4][4];

    int bi = blockIdx.x;
    int img = bi >> 8;
    int t = bi & 255;
    int y0 = (t >> 4) << 5;
    int x0 = (t & 15) << 5;
    const float* L = lum + (size_t)img * NPIX;
    const uchar* Ei = E + (size_t)img * NPIX;
    const uchar* Edi = Ed + (size_t)img * NPIX;

    // ---- stage inputs (zero outside image: contributes 0 to all sums) ----
    for (int i = threadIdx.x; i < VS * VS; i += 256) {
        int r = i / VS, c = i - r * VS;
        int gy = y0 - 3 + r, gx = x0 - 3 + c;
        float l = 0.0f; unsigned m = 0;
        if ((unsigned)gy < HH && (unsigned)gx < WW) {
            int q = gy * WW + gx;
            l = L[q];
            unsigned e = Ei[q], ed = Edi[q];
            m = (e ^ 1u) | ((ed ^ 1u) << 1);
        }
        S[i] = make_uint2(__float_as_uint(l), m);
    }
    __syncthreads();

    // ---- phase 1: horizontal 7-sums for 38 rows x 32 cols ----
    for (int i = threadIdx.x; i < VS * 32; i += 256) {
        int r = i >> 5, c = i & 31;
        const uint2* row = &S[r * VS + c];
        float cu = 0, s1u = 0, s2u = 0, cv = 0, s1v = 0, s2v = 0;
#pragma unroll
        for (int dx = 0; dx < 7; ++dx) {
            uint2 tv = row[dx];
            float l = __uint_as_float(tv.x);
            float u = (float)(tv.y & 1u);
            float v = (float)(tv.y >> 1);
            float ul = u * l, vl = v * l;
            cu += u; cv += v;
            s1u += ul; s2u = fmaf(ul, l, s2u);
            s1v += vl; s2v = fmaf(vl, l, s2v);
        }
        float* h = &Hs[i * HSTRIDE];
        h[0] = cu; h[1] = s1u; h[2] = s2u; h[3] = cv; h[4] = s1v; h[5] = s2v;
    }
    __syncthreads();

    // ---- phase 2: vertical 7-sums + variance + per-thread accumulate ----
    float c0 = 0, c1 = 0, c2 = 0, c3 = 0;
#pragma unroll
    for (int k = 0; k < 4; ++k) {
        int j = threadIdx.x + (k << 8);
        int y = j >> 5, x = j & 31;
        float cu = 0, s1u = 0, s2u = 0, cv = 0, s1v = 0, s2v = 0;
#pragma unroll
        for (int dy = 0; dy < 7; ++dy) {
            const float* h = &Hs[((y + dy) * 32 + x) * HSTRIDE];
            cu += h[0]; s1u += h[1]; s2u += h[2];
            cv += h[3]; s1v += h[4]; s2v += h[5];
        }
        unsigned m0 = S[(y + 3) * VS + (x + 3)].y;
        float u0 = (float)(m0 & 1u), v0 = (float)(m0 >> 1);
        float mb0 = v0;
        float mp0 = u0 * (1.0f - v0);

        float cp = cu - cv, s1p = s1u - s1v, s2p = s2u - s2v;
        float Cp = fmaxf(cp, 1.0f);
        float meanp = s1p / Cp;
        float varp = fmaxf(s2p / Cp - meanp * meanp, 0.0f);
        float Cb = fmaxf(cv, 1.0f);
        float meanb = s1v / Cb;
        float varb = fmaxf(s2v / Cb - meanb * meanb, 0.0f);

        c0 += varp * mp0; c1 += mp0;
        c2 += varb * mb0; c3 += mb0;
    }

    int lane = threadIdx.x & 63;
    int wid = threadIdx.x >> 6;
    c0 = wave_reduce(c0); c1 = wave_reduce(c1); c2 = wave_reduce(c2); c3 = wave_reduce(c3);
    if (lane == 0) { red[wid][0] = c0; red[wid][1] = c1; red[wid][2] = c2; red[wid][3] = c3; }
    __syncthreads();
    if (threadIdx.x == 0) {
        double t0 = 0, t1 = 0, t2 = 0, t3 = 0;
        for (int w = 0; w < 4; ++w) { t0 += red[w][0]; t1 += red[w][1]; t2 += red[w][2]; t3 += red[w][3]; }
        atomicAdd(&acc[img * 4 + 0], t0);
        atomicAdd(&acc[img * 4 + 1], t1);
        atomicAdd(&acc[img * 4 + 2], t2);
        atomicAdd(&acc[img * 4 + 3], t3);
    }
}

// ---------------- Stage 5a: per-image ringing flags ----------------
__global__ void k_flags(const double* __restrict__ acc, float* __restrict__ flags) {
    int i = threadIdx.x;
    if (i >= NIMG) return;
    const double* a = acc + (size_t)i * 4;
    double vp = a[0] / fmax(a[1], 1.0);
    double vb = a[2] / fmax(a[3], 1.0);
    flags[i] = ((vp / (vb + 1e-12)) > 2.0) ? 1.0f : 0.0f;
}

// ---------------- Stage 5b: output (uchar4/float4 vectorized) ----------------
__global__ __launch_bounds__(256) void k_out(const uchar4* __restrict__ E,
                                             const uchar4* __restrict__ Ed,
                                             const float* __restrict__ flags,
                                             float4* __restrict__ out) {
    int idx = blockIdx.x * 256 + threadIdx.x;   // BATCH * NPIX/4 threads
    int b = idx >> 16;
    int p = idx & 65535;
    float fr = flags[b], ft = flags[b + BATCH];
    uchar4 er = E[(size_t)b * 65536 + p];
    uchar4 edr = Ed[(size_t)b * 65536 + p];
    uchar4 et = E[(size_t)(b + BATCH) * 65536 + p];
    uchar4 edt = Ed[(size_t)(b + BATCH) * 65536 + p];
    float4 o;
    o.x = fmaxf((float)(edt.x & (et.x ^ 1)) * ft - (float)(edr.x & (er.x ^ 1)) * fr, 0.0f);
    o.y = fmaxf((float)(edt.y & (et.y ^ 1)) * ft - (float)(edr.y & (er.y ^ 1)) * fr, 0.0f);
    o.z = fmaxf((float)(edt.z & (et.z ^ 1)) * ft - (float)(edr.z & (er.z ^ 1)) * fr, 0.0f);
    o.w = fmaxf((float)(edt.w & (et.w ^ 1)) * ft - (float)(edr.w & (er.w ^ 1)) * fr, 0.0f);
    out[idx] = o;
}

extern "C" void kernel_launch(void* const* d_in, const int* in_sizes, int n_in,
                              void* d_out, int out_size, void* d_ws, size_t ws_size,
                              hipStream_t stream) {
    const float* ref = (const float*)d_in[0];
    const float* tgt = (const float*)d_in[1];
    float* out = (float*)d_out;

    char* ws = (char*)d_ws;
    double* acc = (double*)ws;                       // 32*4 doubles = 1 KB
    float* flags = (float*)(ws + 1024);              // 32 floats
    float* lum = (float*)(ws + 2048);                // 32 MB
    uchar* E = (uchar*)(ws + 2048 + (size_t)NIMG * NPIX * 4);   // 8 MB
    uchar* Ed = E + (size_t)NIMG * NPIX;             // 8 MB

    hipMemsetAsync(acc, 0, NIMG * 4 * sizeof(double), stream);

    int nAll = NIMG * NPIX;          // 8388608
    k_lum<<<nAll / 4 / 256, 256, 0, stream>>>((const float4*)ref, (const float4*)tgt, (float4*)lum);
    k_sobel_dilate<<<NIMG * 256, 256, 0, stream>>>(lum, E, Ed);
    k_var<<<NIMG * 256, 256, 0, stream>>>(lum, E, Ed, acc);
    k_flags<<<1, 64, 0, stream>>>(acc, flags);
    k_out<<<BATCH * NPIX / 4 / 256, 256, 0, stream>>>((const uchar4*)E, (const uchar4*)Ed, flags, (float4*)out);
}